// Round 13
// baseline (209.068 us; speedup 1.0000x reference)
//
#include <hip/hip_runtime.h>
#include <math.h>

#define LOOKBACK 336
#define NFEAT    164
#define HORIZON  96
#define DMODEL   64
#define DSTATE   16
#define DINNER   128
#define MLPH     64
#define BATCH    512
#define XCP      132
#define NG       4      // channel-groups (time segments) per block
#define GSEG     84     // timesteps per group
#define CHK      12     // timesteps per chunk
#define NCH      7      // chunks per group (7*12 = 84)

// pooled LDS (floats): xprojT | xc | Bsh | dtraw ; epilogue overlays hpart/dsum
#define OFF_XPROJ 0
#define OFF_XC    (20*XCP)                          // 2640
#define OFF_BSH   (OFF_XC + NG*CHK*XCP)             // 2640+6336 = 8976
#define OFF_DTRAW (OFF_BSH + NG*CHK*DSTATE)         // 9744
#define POOL_FLTS (OFF_DTRAW + NG*CHK*4)            // 9936

typedef float v2f __attribute__((ext_vector_type(2)));

__device__ __forceinline__ float fast_rcp(float x) { return __builtin_amdgcn_rcpf(x); }
__device__ __forceinline__ float silu_f(float x) {
    return x * fast_rcp(1.f + __expf(-x));
}

__global__ __launch_bounds__(512, 2) void mamba_one(
    const float* __restrict__ x_raw,   const float* __restrict__ x_features,
    const float* __restrict__ embed_W, const float* __restrict__ embed_b,
    const float* __restrict__ in_W,
    const float* __restrict__ conv_W,  const float* __restrict__ conv_b,
    const float* __restrict__ xproj_W, const float* __restrict__ dt_W,
    const float* __restrict__ dt_b,    const float* __restrict__ A_log,
    const float* __restrict__ Dvec,    const float* __restrict__ out_W,
    const float* __restrict__ mlp_W1,  const float* __restrict__ mlp_b1,
    const float* __restrict__ mlp_W2,  const float* __restrict__ mlp_b2,
    const float* __restrict__ head_W,  const float* __restrict__ head_b,
    float* __restrict__ out)
{
    __shared__ __align__(16) float pool[POOL_FLTS];
    __shared__ __align__(16) float xrl[344];        // xrl[i]=x_raw[i-3], pad i<3
    __shared__ float xcl[DINNER], zsil[DINNER], Cl[DSTATE], yv[DINNER];
    __shared__ float hfin[96], mlph[MLPH];

    float* xprojT = pool + OFF_XPROJ;               // [20][XCP]
    float* xcS    = pool + OFF_XC;                  // [NG][CHK*XCP]
    float* BshS   = pool + OFF_BSH;                 // [NG][CHK][16]
    float* dtrawS = pool + OFF_DTRAW;               // [NG][CHK][4]

    const int tid = threadIdx.x;
    const int b   = blockIdx.x;
    const int g   = tid >> 7;            // group 0..3 (2 waves, wave-uniform)
    const int ch  = tid & 127;

    // ---- staging ----
    for (int i = tid; i < 339; i += 512)
        xrl[i] = (i >= 3) ? x_raw[b*LOOKBACK + i - 3] : 0.f;
    for (int idx = tid; idx < 20*DINNER; idx += 512) {
        int jj = idx >> 7, d = idx & 127;
        xprojT[jj*XCP + d] = xproj_W[d*36 + jj];
    }

    // ---- per-thread channel params (embed_* uniform -> scalar loads) ----
    float w1 = 0.f, w0 = 0.f;
    for (int dm = 0; dm < DMODEL; ++dm) {
        float w = in_W[dm*(2*DINNER) + ch];
        w1 = fmaf(embed_W[dm], w, w1);
        w0 = fmaf(embed_b[dm], w, w0);
    }
    const float4 cw = *(const float4*)&conv_W[ch*4];
    const float  cb = conv_b[ch];
    const float dtw0 = dt_W[ch],       dtw1 = dt_W[128 + ch],
                dtw2 = dt_W[256 + ch], dtw3 = dt_W[384 + ch];
    const float dtb_r = dt_b[ch];
    bool structured = true;
    #pragma unroll
    for (int i = 0; i < 16; ++i) {
        float a = __expf(A_log[ch*DSTATE + i]);
        float ex = (float)(i + 1);
        structured = structured && (fabsf(a - ex) < 1e-3f * ex);
    }
    const bool sfast = __all(structured);

    // A2 task mapping (constant per thread)
    const int aq  = ch & 3;              // d-quarter
    const int ajp = (ch >> 2) % 10;      // column pair (ajp, ajp+10)
    const int atg = ch / 40;             // t-group of 4 rows
    __syncthreads();   // xrl/xprojT ready

    float cur[CHK], nxt[CHK];            // conv outputs for this (g,ch)

    // ---- conv chunk 0 (into cur + LDS) ----
    {
        float* xw = xcS + g*(CHK*XCP);
        const float* xr = &xrl[g*GSEG];
        if (g == 0) {        // zero-padded taps at sequence start
            #pragma unroll
            for (int tt = 0; tt < CHK; ++tt) {
                float acc = cb;
                if (tt >= 3) acc = fmaf(fmaf(xr[tt],   w1, w0), cw.x, acc);
                if (tt >= 2) acc = fmaf(fmaf(xr[tt+1], w1, w0), cw.y, acc);
                if (tt >= 1) acc = fmaf(fmaf(xr[tt+2], w1, w0), cw.z, acc);
                acc = fmaf(fmaf(xr[tt+3], w1, w0), cw.w, acc);
                float v = silu_f(acc);
                cur[tt] = v;
                xw[tt*XCP + ch] = v;
            }
        } else {
            float e0 = fmaf(xr[0], w1, w0);
            float e1 = fmaf(xr[1], w1, w0);
            float e2 = fmaf(xr[2], w1, w0);
            #pragma unroll
            for (int tt = 0; tt < CHK; ++tt) {
                float e3 = fmaf(xr[tt+3], w1, w0);
                float acc = cb + e0*cw.x + e1*cw.y + e2*cw.z + e3*cw.w;
                float v = silu_f(acc);
                cur[tt] = v;
                xw[tt*XCP + ch] = v;
                e0 = e1; e1 = e2; e2 = e3;
            }
        }
    }
    __syncthreads();

    // ---- main loop: A2(c) | bar | scan(c) + conv(c+1 over xc) | bar ----
    v2f h01={0,0},h23={0,0},h45={0,0},h67={0,0},
        h89={0,0},hAB={0,0},hCD={0,0},hEF={0,0};
    float dacc = 0.f;

    for (int c = 0; c < NCH; ++c) {
        // A2: [12x128]@[128x20]; 120 tasks = 3tg x 10jp x 4quarter
        if (ch < 120) {
            const int t0 = atg*4;
            const int d0 = aq*32;
            const float* p0 = &xprojT[ajp*XCP + d0];
            const float* p1 = &xprojT[(ajp+10)*XCP + d0];
            const float* xb = xcS + g*(CHK*XCP) + d0;
            v2f aj0={0,0}, aj1={0,0}, aj2={0,0}, aj3={0,0};
            v2f bj0={0,0}, bj1={0,0}, bj2={0,0}, bj3={0,0};
            #pragma unroll
            for (int i = 0; i < 8; ++i) {
                float4 q0 = *(const float4*)(p0 + 4*i);
                float4 q1 = *(const float4*)(p1 + 4*i);
                v2f q0l={q0.x,q0.y}, q0h={q0.z,q0.w};
                v2f q1l={q1.x,q1.y}, q1h={q1.z,q1.w};
                float4 x0 = *(const float4*)(xb + (t0+0)*XCP + 4*i);
                float4 x1 = *(const float4*)(xb + (t0+1)*XCP + 4*i);
                float4 x2 = *(const float4*)(xb + (t0+2)*XCP + 4*i);
                float4 x3 = *(const float4*)(xb + (t0+3)*XCP + 4*i);
                v2f x0l={x0.x,x0.y}, x0h={x0.z,x0.w};
                v2f x1l={x1.x,x1.y}, x1h={x1.z,x1.w};
                v2f x2l={x2.x,x2.y}, x2h={x2.z,x2.w};
                v2f x3l={x3.x,x3.y}, x3h={x3.z,x3.w};
                aj0 = __builtin_elementwise_fma(x0l,q0l,aj0);
                aj0 = __builtin_elementwise_fma(x0h,q0h,aj0);
                aj1 = __builtin_elementwise_fma(x1l,q0l,aj1);
                aj1 = __builtin_elementwise_fma(x1h,q0h,aj1);
                aj2 = __builtin_elementwise_fma(x2l,q0l,aj2);
                aj2 = __builtin_elementwise_fma(x2h,q0h,aj2);
                aj3 = __builtin_elementwise_fma(x3l,q0l,aj3);
                aj3 = __builtin_elementwise_fma(x3h,q0h,aj3);
                bj0 = __builtin_elementwise_fma(x0l,q1l,bj0);
                bj0 = __builtin_elementwise_fma(x0h,q1h,bj0);
                bj1 = __builtin_elementwise_fma(x1l,q1l,bj1);
                bj1 = __builtin_elementwise_fma(x1h,q1h,bj1);
                bj2 = __builtin_elementwise_fma(x2l,q1l,bj2);
                bj2 = __builtin_elementwise_fma(x2h,q1h,bj2);
                bj3 = __builtin_elementwise_fma(x3l,q1l,bj3);
                bj3 = __builtin_elementwise_fma(x3h,q1h,bj3);
            }
            float s0 = aj0.x+aj0.y, s1 = aj1.x+aj1.y,
                  s2 = aj2.x+aj2.y, s3 = aj3.x+aj3.y;
            float u0 = bj0.x+bj0.y, u1 = bj1.x+bj1.y,
                  u2 = bj2.x+bj2.y, u3 = bj3.x+bj3.y;
            s0 += __shfl_xor(s0,1); s0 += __shfl_xor(s0,2);
            s1 += __shfl_xor(s1,1); s1 += __shfl_xor(s1,2);
            s2 += __shfl_xor(s2,1); s2 += __shfl_xor(s2,2);
            s3 += __shfl_xor(s3,1); s3 += __shfl_xor(s3,2);
            u0 += __shfl_xor(u0,1); u0 += __shfl_xor(u0,2);
            u1 += __shfl_xor(u1,1); u1 += __shfl_xor(u1,2);
            u2 += __shfl_xor(u2,1); u2 += __shfl_xor(u2,2);
            u3 += __shfl_xor(u3,1); u3 += __shfl_xor(u3,2);
            // lane q writes row t0+q, cols ajp and ajp+10
            const int t = t0 + aq;
            float sv = (aq==0)?s0:(aq==1)?s1:(aq==2)?s2:s3;
            float uv = (aq==0)?u0:(aq==1)?u1:(aq==2)?u2:u3;
            if (ajp < 4) dtrawS[(g*CHK + t)*4 + ajp] = sv;
            else         BshS[(g*CHK + t)*DSTATE + (ajp-4)] = sv;
            BshS[(g*CHK + t)*DSTATE + (ajp+6)] = uv;
        }
        __syncthreads();

        // scan chunk c (u from cur regs; B/dt broadcast from LDS)
        if (__builtin_expect(sfast, 1)) {
            #pragma unroll
            for (int tt = 0; tt < CHK; ++tt) {
                float4 dr = *(const float4*)&dtrawS[(g*CHK + tt)*4];
                float dv = fmaf(dr.x, dtw0, fmaf(dr.y, dtw1,
                           fmaf(dr.z, dtw2, fmaf(dr.w, dtw3, dtb_r))));
                float e  = __expf(dv);
                float p  = 1.f + e;
                float r  = fast_rcp(p);                  // exp(-delta)
                float dl = (dv > 80.f) ? dv : __logf(p); // delta
                dacc += dl;
                float ux = dl * cur[tt];
                const float* Br = &BshS[(g*CHK + tt)*DSTATE];
                float4 B0 = *(const float4*)(Br);
                float4 B1 = *(const float4*)(Br + 4);
                float4 B2 = *(const float4*)(Br + 8);
                float4 B3 = *(const float4*)(Br + 12);
                float r2 = r*r;
                v2f r2v = {r2, r2};
                v2f p01 = {r, r2};
                v2f p23 = p01*r2v, p45 = p23*r2v, p67 = p45*r2v, p89 = p67*r2v,
                    pAB = p89*r2v, pCD = pAB*r2v, pEF = pCD*r2v;
                v2f uxv = {ux, ux};
                h01 = __builtin_elementwise_fma(p01, h01, uxv*(v2f){B0.x,B0.y});
                h23 = __builtin_elementwise_fma(p23, h23, uxv*(v2f){B0.z,B0.w});
                h45 = __builtin_elementwise_fma(p45, h45, uxv*(v2f){B1.x,B1.y});
                h67 = __builtin_elementwise_fma(p67, h67, uxv*(v2f){B1.z,B1.w});
                h89 = __builtin_elementwise_fma(p89, h89, uxv*(v2f){B2.x,B2.y});
                hAB = __builtin_elementwise_fma(pAB, hAB, uxv*(v2f){B2.z,B2.w});
                hCD = __builtin_elementwise_fma(pCD, hCD, uxv*(v2f){B3.x,B3.y});
                hEF = __builtin_elementwise_fma(pEF, hEF, uxv*(v2f){B3.z,B3.w});
            }
        } else {
            const float* Arow = A_log + ch*DSTATE;
            for (int tt = 0; tt < CHK; ++tt) {
                float4 dr = *(const float4*)&dtrawS[(g*CHK + tt)*4];
                float dv = fmaf(dr.x, dtw0, fmaf(dr.y, dtw1,
                           fmaf(dr.z, dtw2, fmaf(dr.w, dtw3, dtb_r))));
                float e  = __expf(dv);
                float dl = (dv > 15.f) ? dv : __logf(1.f + e);
                dacc += dl;
                float ux = dl * cur[tt];
                const float* Br = &BshS[(g*CHK + tt)*DSTATE];
                float hv[16] = {h01.x,h01.y,h23.x,h23.y,h45.x,h45.y,h67.x,h67.y,
                                h89.x,h89.y,hAB.x,hAB.y,hCD.x,hCD.y,hEF.x,hEF.y};
                for (int i = 0; i < 16; ++i)
                    hv[i] = fmaf(__expf(-__expf(Arow[i])*dl), hv[i], ux*Br[i]);
                h01=(v2f){hv[0],hv[1]};   h23=(v2f){hv[2],hv[3]};
                h45=(v2f){hv[4],hv[5]};   h67=(v2f){hv[6],hv[7]};
                h89=(v2f){hv[8],hv[9]};   hAB=(v2f){hv[10],hv[11]};
                hCD=(v2f){hv[12],hv[13]}; hEF=(v2f){hv[14],hv[15]};
            }
        }

        // conv chunk c+1 overwrites xcS (A2 finished with it last phase)
        if (c + 1 < NCH) {
            float* xw = xcS + g*(CHK*XCP);
            const float* xr = &xrl[g*GSEG + (c+1)*CHK];
            float e0 = fmaf(xr[0], w1, w0);
            float e1 = fmaf(xr[1], w1, w0);
            float e2 = fmaf(xr[2], w1, w0);
            #pragma unroll
            for (int tt = 0; tt < CHK; ++tt) {
                float e3 = fmaf(xr[tt+3], w1, w0);
                float acc = cb + e0*cw.x + e1*cw.y + e2*cw.z + e3*cw.w;
                float v = silu_f(acc);
                nxt[tt] = v;
                xw[tt*XCP + ch] = v;
                e0 = e1; e1 = e2; e2 = e3;
            }
            if (g == NG-1 && c + 1 == NCH-1) xcl[ch] = nxt[CHK-1];   // t = 335
            #pragma unroll
            for (int tt = 0; tt < CHK; ++tt) cur[tt] = nxt[tt];
        }
        __syncthreads();
    }

    // ---- write partials to LDS overlay (SoA: conflict-free b32) ----
    float* hpart = pool;                 // [16][512]
    float* dsum  = pool + 16*512;        // [512]
    {
        const int gid = g*128 + ch;
        float hv[16] = {h01.x,h01.y,h23.x,h23.y,h45.x,h45.y,h67.x,h67.y,
                        h89.x,h89.y,hAB.x,hAB.y,hCD.x,hCD.y,hEF.x,hEF.y};
        #pragma unroll
        for (int i = 0; i < 16; ++i) hpart[i*512 + gid] = hv[i];
        dsum[gid] = dacc;
    }
    __syncthreads();

    // ---- E1 (parallel): combine | z-gate | C | mlp1 ----
    float H[16];
    if (tid < 128) {
        #pragma unroll
        for (int i = 0; i < 16; ++i) H[i] = hpart[i*512 + tid];
        for (int gg = 1; gg < NG; ++gg) {
            float D = dsum[gg*128 + tid];
            if (structured) {
                float r = __expf(-D);
                float pw = 1.f;
                #pragma unroll
                for (int i = 0; i < 16; ++i) {
                    pw *= r;                      // r^(i+1)
                    H[i] = fmaf(pw, H[i], hpart[i*512 + gg*128 + tid]);
                }
            } else {
                #pragma unroll
                for (int i = 0; i < 16; ++i)
                    H[i] = fmaf(__expf(-__expf(A_log[tid*DSTATE+i])*D),
                                H[i], hpart[i*512 + gg*128 + tid]);
            }
        }
    } else if (tid < 256) {
        const int c2 = tid - 128;                 // z-gate channel
        float a1 = 0.f, a0 = 0.f;
        for (int dm = 0; dm < DMODEL; ++dm) {
            float w = in_W[dm*(2*DINNER) + DINNER + c2];
            a1 = fmaf(embed_W[dm], w, a1);
            a0 = fmaf(embed_b[dm], w, a0);
        }
        float zv = fmaf(xrl[338], a1, a0);        // x_raw[335]
        zsil[c2] = silu_f(zv);
    } else if (tid < 320) {
        const int lane = tid - 256;               // C at t=335 (one wave)
        const int n = lane & 15, q = lane >> 4;
        float acc = 0.f;
        for (int d = q*32; d < q*32 + 32; ++d)
            acc = fmaf(xcl[d], xproj_W[d*36 + 20 + n], acc);
        acc += __shfl_xor(acc, 16);
        acc += __shfl_xor(acc, 32);
        if (lane < 16) Cl[n] = acc;
    } else if (tid >= 384) {
        const int lane = tid - 384;               // mlp1 (2 waves)
        const int j = lane >> 1, k = lane & 1;
        const float* xf = x_features + b*NFEAT;
        float acc = 0.f;
        const int f0 = k*82, f1 = (k ? NFEAT : 82);
        for (int f = f0; f < f1; ++f)
            acc = fmaf(xf[f], mlp_W1[f*MLPH + j], acc);
        acc += __shfl_xor(acc, 1);
        if (k == 0) mlph[j] = fmaxf(acc + mlp_b1[j], 0.f);
    }
    __syncthreads();

    // ---- E2: y (tid<128) | mlp2 (tid 128..191) ----
    if (tid < 128) {
        float acc = 0.f;
        #pragma unroll
        for (int i = 0; i < 16; ++i) acc = fmaf(H[i], Cl[i], acc);
        float y = acc + xcl[tid]*Dvec[tid];
        yv[tid] = y * zsil[tid];
    } else if (tid < 192) {
        const int lane = tid - 128;
        const int j = lane >> 1, k = lane & 1;
        float acc = 0.f;
        for (int kk = k*32; kk < k*32 + 32; ++kk)
            acc = fmaf(mlph[kk], mlp_W2[kk*32 + j], acc);
        acc += __shfl_xor(acc, 1);
        if (k == 0) hfin[64 + j] = acc + mlp_b2[j];
    }
    __syncthreads();

    // ---- E3: out projection (tid<256) ----
    if (tid < 256) {
        const int o = tid >> 2, k = tid & 3;
        float acc = 0.f;
        for (int d = k*32; d < k*32 + 32; ++d)
            acc = fmaf(yv[d], out_W[d*DMODEL + o], acc);
        acc += __shfl_xor(acc, 1);
        acc += __shfl_xor(acc, 2);
        if (k == 0) hfin[o] = acc;
    }
    __syncthreads();

    // ---- E4: head ----
    if (tid < 192) {
        const int o = tid >> 1, k = tid & 1;
        float acc = 0.f;
        for (int i = k*48; i < k*48 + 48; ++i)
            acc = fmaf(hfin[i], head_W[i*HORIZON + o], acc);
        acc += __shfl_xor(acc, 1);
        if (k == 0) out[b*HORIZON + o] = acc + head_b[o];
    }
}

extern "C" void kernel_launch(void* const* d_in, const int* in_sizes, int n_in,
                              void* d_out, int out_size, void* d_ws, size_t ws_size,
                              hipStream_t stream) {
    (void)in_sizes; (void)n_in; (void)out_size; (void)d_ws; (void)ws_size;
    mamba_one<<<BATCH, 512, 0, stream>>>(
        (const float*)d_in[0],  (const float*)d_in[1],  (const float*)d_in[2],
        (const float*)d_in[3],  (const float*)d_in[4],  (const float*)d_in[5],
        (const float*)d_in[6],  (const float*)d_in[7],  (const float*)d_in[8],
        (const float*)d_in[9],  (const float*)d_in[10], (const float*)d_in[11],
        (const float*)d_in[12], (const float*)d_in[13], (const float*)d_in[14],
        (const float*)d_in[15], (const float*)d_in[16], (const float*)d_in[17],
        (const float*)d_in[18], (float*)d_out);
}

// Round 14
// 207.131 us; speedup vs baseline: 1.0093x; 1.0093x over previous
//
#include <hip/hip_runtime.h>
#include <math.h>

#define LOOKBACK 336
#define NFEAT    164
#define HORIZON  96
#define DMODEL   64
#define DSTATE   16
#define DINNER   128
#define MLPH     64
#define BATCH    512
#define XCP      132
#define NG       4      // channel-groups (time segments) per block
#define GSEG     84     // timesteps per group
#define CHK      12     // timesteps per chunk
#define NCH      7      // chunks per group (7*12 = 84)

typedef float v2f __attribute__((ext_vector_type(2)));

__device__ __forceinline__ float fast_rcp(float x) { return __builtin_amdgcn_rcpf(x); }
__device__ __forceinline__ float silu_f(float x) {
    return x * fast_rcp(1.f + __expf(-x));
}

__global__ __launch_bounds__(512, 2) void mamba_one(
    const float* __restrict__ x_raw,   const float* __restrict__ x_features,
    const float* __restrict__ embed_W, const float* __restrict__ embed_b,
    const float* __restrict__ in_W,
    const float* __restrict__ conv_W,  const float* __restrict__ conv_b,
    const float* __restrict__ xproj_W, const float* __restrict__ dt_W,
    const float* __restrict__ dt_b,    const float* __restrict__ A_log,
    const float* __restrict__ Dvec,    const float* __restrict__ out_W,
    const float* __restrict__ mlp_W1,  const float* __restrict__ mlp_b1,
    const float* __restrict__ mlp_W2,  const float* __restrict__ mlp_b2,
    const float* __restrict__ head_W,  const float* __restrict__ head_b,
    float* __restrict__ out)
{
    __shared__ __align__(16) float xrl[344];              // xrl[i]=x_raw[i-3]
    __shared__ __align__(16) float xprojT[20*XCP];
    __shared__ __align__(16) float xcbuf[2][NG][CHK*XCP]; // double-buffered conv out
    __shared__ __align__(16) float Bsh[NG][CHK][DSTATE];
    __shared__ __align__(16) float dtraw[NG][CHK][4];
    __shared__ float xcl[DINNER], zsil[DINNER], Cl[DSTATE], yv[DINNER];
    __shared__ float hfin[96], mlph[MLPH];

    const int tid = threadIdx.x;
    const int b   = blockIdx.x;
    const int g   = tid >> 7;            // group 0..3 (2 waves, wave-uniform)
    const int ch  = tid & 127;

    // ---- staging ----
    for (int i = tid; i < 339; i += 512)
        xrl[i] = (i >= 3) ? x_raw[b*LOOKBACK + i - 3] : 0.f;
    for (int idx = tid; idx < 20*DINNER; idx += 512) {
        int jj = idx >> 7, d = idx & 127;
        xprojT[jj*XCP + d] = xproj_W[d*36 + jj];
    }

    // ---- per-thread channel params ----
    float w1 = 0.f, w0 = 0.f;
    for (int dm = 0; dm < DMODEL; ++dm) {
        float w = in_W[dm*(2*DINNER) + ch];
        w1 = fmaf(embed_W[dm], w, w1);
        w0 = fmaf(embed_b[dm], w, w0);
    }
    const float4 cw = *(const float4*)&conv_W[ch*4];
    const float  cb = conv_b[ch];
    const float dtw0 = dt_W[ch],       dtw1 = dt_W[128 + ch],
                dtw2 = dt_W[256 + ch], dtw3 = dt_W[384 + ch];
    const float dtb_r = dt_b[ch];
    bool structured = true;
    #pragma unroll
    for (int i = 0; i < 16; ++i) {
        float a = __expf(A_log[ch*DSTATE + i]);
        float ex = (float)(i + 1);
        structured = structured && (fabsf(a - ex) < 1e-3f * ex);
    }
    const bool sfast = __all(structured);

    // A2 global task map: 480 tasks = tt(12) x jp(10) x dq(4); dq in bits 0-1
    const int a_dq = tid & 3;
    const int a_jp = (tid >> 2) % 10;
    const int a_tt = tid / 40;           // 0..12 (12 -> inactive)
    const bool a_on = (tid < 480);
    __syncthreads();   // xrl/xprojT ready

    float cur[CHK], nxt[CHK];            // conv outputs held in registers

    // ---- conv chunk 0 into buffer 0 (+ cur regs) ----
    {
        float* xw = &xcbuf[0][g][0];
        const float* xr = &xrl[g*GSEG];
        if (g == 0) {        // zero-padded taps at sequence start
            #pragma unroll
            for (int tt = 0; tt < CHK; ++tt) {
                float acc = cb;
                if (tt >= 3) acc = fmaf(fmaf(xr[tt],   w1, w0), cw.x, acc);
                if (tt >= 2) acc = fmaf(fmaf(xr[tt+1], w1, w0), cw.y, acc);
                if (tt >= 1) acc = fmaf(fmaf(xr[tt+2], w1, w0), cw.z, acc);
                acc = fmaf(fmaf(xr[tt+3], w1, w0), cw.w, acc);
                float v = silu_f(acc);
                cur[tt] = v;
                xw[tt*XCP + ch] = v;
            }
        } else {
            float e0 = fmaf(xr[0], w1, w0);
            float e1 = fmaf(xr[1], w1, w0);
            float e2 = fmaf(xr[2], w1, w0);
            #pragma unroll
            for (int tt = 0; tt < CHK; ++tt) {
                float e3 = fmaf(xr[tt+3], w1, w0);
                float acc = cb + e0*cw.x + e1*cw.y + e2*cw.z + e3*cw.w;
                float v = silu_f(acc);
                cur[tt] = v;
                xw[tt*XCP + ch] = v;
                e0 = e1; e1 = e2; e2 = e3;
            }
        }
    }
    __syncthreads();

    // ---- main loop: A2(c) | bar | scan(c) + conv(c+1) | bar ----
    v2f h01={0,0},h23={0,0},h45={0,0},h67={0,0},
        h89={0,0},hAB={0,0},hCD={0,0},hEF={0,0};
    float dacc = 0.f;

    for (int c = 0; c < NCH; ++c) {
        const int buf = c & 1;

        // A2 for ALL groups: xproj rows (jp, jp+10) amortized over 4 groups'
        // xc rows; k-schedule rotated by dq so concurrent dq-lanes hit
        // disjoint banks (4k, 4k+8, 4k+16, 4k+24).
        if (a_on) {
            const float* xb = &xcbuf[buf][0][0];
            const float* p0 = &xprojT[a_jp*XCP];
            const float* p1 = &xprojT[(a_jp+10)*XCP];
            v2f acc0[NG], acc1[NG];
            #pragma unroll
            for (int gg = 0; gg < NG; ++gg) { acc0[gg]=(v2f){0,0}; acc1[gg]=(v2f){0,0}; }
            #pragma unroll
            for (int k = 0; k < 8; ++k) {
                const int di = a_dq*32 + 4*((k + 2*a_dq) & 7);
                float4 q0 = *(const float4*)(p0 + di);
                float4 q1 = *(const float4*)(p1 + di);
                v2f q0l={q0.x,q0.y}, q0h={q0.z,q0.w};
                v2f q1l={q1.x,q1.y}, q1h={q1.z,q1.w};
                #pragma unroll
                for (int gg = 0; gg < NG; ++gg) {
                    float4 xv = *(const float4*)(xb + gg*(CHK*XCP) + a_tt*XCP + di);
                    v2f xl={xv.x,xv.y}, xh={xv.z,xv.w};
                    acc0[gg] = __builtin_elementwise_fma(xl, q0l, acc0[gg]);
                    acc0[gg] = __builtin_elementwise_fma(xh, q0h, acc0[gg]);
                    acc1[gg] = __builtin_elementwise_fma(xl, q1l, acc1[gg]);
                    acc1[gg] = __builtin_elementwise_fma(xh, q1h, acc1[gg]);
                }
            }
            float s0[NG], s1[NG];
            #pragma unroll
            for (int gg = 0; gg < NG; ++gg) {
                s0[gg] = acc0[gg].x + acc0[gg].y;
                s1[gg] = acc1[gg].x + acc1[gg].y;
                s0[gg] += __shfl_xor(s0[gg], 1);
                s0[gg] += __shfl_xor(s0[gg], 2);
                s1[gg] += __shfl_xor(s1[gg], 1);
                s1[gg] += __shfl_xor(s1[gg], 2);
            }
            // lane dq writes group dq's outputs for (tt, jp) and (tt, jp+10)
            float v0 = (a_dq==0)?s0[0]:(a_dq==1)?s0[1]:(a_dq==2)?s0[2]:s0[3];
            float v1 = (a_dq==0)?s1[0]:(a_dq==1)?s1[1]:(a_dq==2)?s1[2]:s1[3];
            if (a_jp < 4) dtraw[a_dq][a_tt][a_jp]      = v0;
            else          Bsh[a_dq][a_tt][a_jp - 4]    = v0;
            Bsh[a_dq][a_tt][a_jp + 6]                  = v1;   // col jp+10
        }
        __syncthreads();

        // scan chunk c (u from cur regs; dt/B broadcast reads)
        if (__builtin_expect(sfast, 1)) {
            #pragma unroll
            for (int tt = 0; tt < CHK; ++tt) {
                float4 dr = *(const float4*)&dtraw[g][tt][0];    // broadcast
                float dv = fmaf(dr.x, dtw0, fmaf(dr.y, dtw1,
                           fmaf(dr.z, dtw2, fmaf(dr.w, dtw3, dtb_r))));
                float e  = __expf(dv);
                float p  = 1.f + e;
                float r  = fast_rcp(p);                  // exp(-delta)
                float dl = (dv > 80.f) ? dv : __logf(p); // delta
                dacc += dl;
                float ux = dl * cur[tt];
                float4 B0 = *(const float4*)&Bsh[g][tt][0];
                float4 B1 = *(const float4*)&Bsh[g][tt][4];
                float4 B2 = *(const float4*)&Bsh[g][tt][8];
                float4 B3 = *(const float4*)&Bsh[g][tt][12];
                float r2 = r*r;
                v2f r2v = {r2, r2};
                v2f p01 = {r, r2};
                v2f p23 = p01*r2v, p45 = p23*r2v, p67 = p45*r2v, p89 = p67*r2v,
                    pAB = p89*r2v, pCD = pAB*r2v, pEF = pCD*r2v;
                v2f uxv = {ux, ux};
                h01 = __builtin_elementwise_fma(p01, h01, uxv*(v2f){B0.x,B0.y});
                h23 = __builtin_elementwise_fma(p23, h23, uxv*(v2f){B0.z,B0.w});
                h45 = __builtin_elementwise_fma(p45, h45, uxv*(v2f){B1.x,B1.y});
                h67 = __builtin_elementwise_fma(p67, h67, uxv*(v2f){B1.z,B1.w});
                h89 = __builtin_elementwise_fma(p89, h89, uxv*(v2f){B2.x,B2.y});
                hAB = __builtin_elementwise_fma(pAB, hAB, uxv*(v2f){B2.z,B2.w});
                hCD = __builtin_elementwise_fma(pCD, hCD, uxv*(v2f){B3.x,B3.y});
                hEF = __builtin_elementwise_fma(pEF, hEF, uxv*(v2f){B3.z,B3.w});
            }
        } else {
            const float* Arow = A_log + ch*DSTATE;
            for (int tt = 0; tt < CHK; ++tt) {
                float4 dr = *(const float4*)&dtraw[g][tt][0];
                float dv = fmaf(dr.x, dtw0, fmaf(dr.y, dtw1,
                           fmaf(dr.z, dtw2, fmaf(dr.w, dtw3, dtb_r))));
                float e  = __expf(dv);
                float dl = (dv > 15.f) ? dv : __logf(1.f + e);
                dacc += dl;
                float ux = dl * cur[tt];
                const float* Br = &Bsh[g][tt][0];
                float hv[16] = {h01.x,h01.y,h23.x,h23.y,h45.x,h45.y,h67.x,h67.y,
                                h89.x,h89.y,hAB.x,hAB.y,hCD.x,hCD.y,hEF.x,hEF.y};
                for (int i = 0; i < 16; ++i)
                    hv[i] = fmaf(__expf(-__expf(Arow[i])*dl), hv[i], ux*Br[i]);
                h01=(v2f){hv[0],hv[1]};   h23=(v2f){hv[2],hv[3]};
                h45=(v2f){hv[4],hv[5]};   h67=(v2f){hv[6],hv[7]};
                h89=(v2f){hv[8],hv[9]};   hAB=(v2f){hv[10],hv[11]};
                hCD=(v2f){hv[12],hv[13]}; hEF=(v2f){hv[14],hv[15]};
            }
        }

        // conv chunk c+1 into the other buffer (A2(c) read buf; scan used regs)
        if (c + 1 < NCH) {
            float* xw = &xcbuf[buf^1][g][0];
            const float* xr = &xrl[g*GSEG + (c+1)*CHK];
            float e0 = fmaf(xr[0], w1, w0);
            float e1 = fmaf(xr[1], w1, w0);
            float e2 = fmaf(xr[2], w1, w0);
            #pragma unroll
            for (int tt = 0; tt < CHK; ++tt) {
                float e3 = fmaf(xr[tt+3], w1, w0);
                float acc = cb + e0*cw.x + e1*cw.y + e2*cw.z + e3*cw.w;
                float v = silu_f(acc);
                nxt[tt] = v;
                xw[tt*XCP + ch] = v;
                e0 = e1; e1 = e2; e2 = e3;
            }
            if (g == NG-1 && c + 1 == NCH-1) xcl[ch] = nxt[CHK-1];   // t = 335
            #pragma unroll
            for (int tt = 0; tt < CHK; ++tt) cur[tt] = nxt[tt];
        }
        __syncthreads();
    }

    // ---- write partials to LDS overlay (SoA: stride-1 b32, conflict-free) ----
    float* hpart = &xcbuf[0][0][0];      // needs 16*512+512 = 8704 <= 12672
    float* dsum  = hpart + 16*512;
    {
        const int gid = g*128 + ch;
        float hv[16] = {h01.x,h01.y,h23.x,h23.y,h45.x,h45.y,h67.x,h67.y,
                        h89.x,h89.y,hAB.x,hAB.y,hCD.x,hCD.y,hEF.x,hEF.y};
        #pragma unroll
        for (int i = 0; i < 16; ++i) hpart[i*512 + gid] = hv[i];
        dsum[gid] = dacc;
    }
    __syncthreads();

    // ---- E1 (parallel): combine | z-gate | C | mlp1 ----
    float H[16];
    if (tid < 128) {
        #pragma unroll
        for (int i = 0; i < 16; ++i) H[i] = hpart[i*512 + tid];
        for (int gg = 1; gg < NG; ++gg) {
            float D = dsum[gg*128 + tid];
            if (structured) {
                float r = __expf(-D);
                float pw = 1.f;
                #pragma unroll
                for (int i = 0; i < 16; ++i) {
                    pw *= r;                      // r^(i+1)
                    H[i] = fmaf(pw, H[i], hpart[i*512 + gg*128 + tid]);
                }
            } else {
                #pragma unroll
                for (int i = 0; i < 16; ++i)
                    H[i] = fmaf(__expf(-__expf(A_log[tid*DSTATE+i])*D),
                                H[i], hpart[i*512 + gg*128 + tid]);
            }
        }
    } else if (tid < 256) {
        const int c2 = tid - 128;                 // z-gate channel
        float a1 = 0.f, a0 = 0.f;
        for (int dm = 0; dm < DMODEL; ++dm) {
            float w = in_W[dm*(2*DINNER) + DINNER + c2];
            a1 = fmaf(embed_W[dm], w, a1);
            a0 = fmaf(embed_b[dm], w, a0);
        }
        float zv = fmaf(xrl[338], a1, a0);        // x_raw[335]
        zsil[c2] = silu_f(zv);
    } else if (tid < 320) {
        const int lane = tid - 256;               // C at t=335 (one wave)
        const int n = lane & 15, q = lane >> 4;
        float acc = 0.f;
        for (int d = q*32; d < q*32 + 32; ++d)
            acc = fmaf(xcl[d], xproj_W[d*36 + 20 + n], acc);
        acc += __shfl_xor(acc, 16);
        acc += __shfl_xor(acc, 32);
        if (lane < 16) Cl[n] = acc;
    } else if (tid >= 384) {
        const int lane = tid - 384;               // mlp1 (2 waves)
        const int j = lane >> 1, k = lane & 1;
        const float* xf = x_features + b*NFEAT;
        float acc = 0.f;
        const int f0 = k*82, f1 = (k ? NFEAT : 82);
        for (int f = f0; f < f1; ++f)
            acc = fmaf(xf[f], mlp_W1[f*MLPH + j], acc);
        acc += __shfl_xor(acc, 1);
        if (k == 0) mlph[j] = fmaxf(acc + mlp_b1[j], 0.f);
    }
    __syncthreads();

    // ---- E2: y (tid<128) | mlp2 (tid 128..191) ----
    if (tid < 128) {
        float acc = 0.f;
        #pragma unroll
        for (int i = 0; i < 16; ++i) acc = fmaf(H[i], Cl[i], acc);
        float y = acc + xcl[tid]*Dvec[tid];
        yv[tid] = y * zsil[tid];
    } else if (tid < 192) {
        const int lane = tid - 128;
        const int j = lane >> 1, k = lane & 1;
        float acc = 0.f;
        for (int kk = k*32; kk < k*32 + 32; ++kk)
            acc = fmaf(mlph[kk], mlp_W2[kk*32 + j], acc);
        acc += __shfl_xor(acc, 1);
        if (k == 0) hfin[64 + j] = acc + mlp_b2[j];
    }
    __syncthreads();

    // ---- E3: out projection (tid<256) ----
    if (tid < 256) {
        const int o = tid >> 2, k = tid & 3;
        float acc = 0.f;
        for (int d = k*32; d < k*32 + 32; ++d)
            acc = fmaf(yv[d], out_W[d*DMODEL + o], acc);
        acc += __shfl_xor(acc, 1);
        acc += __shfl_xor(acc, 2);
        if (k == 0) hfin[o] = acc;
    }
    __syncthreads();

    // ---- E4: head ----
    if (tid < 192) {
        const int o = tid >> 1, k = tid & 1;
        float acc = 0.f;
        for (int i = k*48; i < k*48 + 48; ++i)
            acc = fmaf(hfin[i], head_W[i*HORIZON + o], acc);
        acc += __shfl_xor(acc, 1);
        if (k == 0) out[b*HORIZON + o] = acc + head_b[o];
    }
}

extern "C" void kernel_launch(void* const* d_in, const int* in_sizes, int n_in,
                              void* d_out, int out_size, void* d_ws, size_t ws_size,
                              hipStream_t stream) {
    (void)in_sizes; (void)n_in; (void)out_size; (void)d_ws; (void)ws_size;
    mamba_one<<<BATCH, 512, 0, stream>>>(
        (const float*)d_in[0],  (const float*)d_in[1],  (const float*)d_in[2],
        (const float*)d_in[3],  (const float*)d_in[4],  (const float*)d_in[5],
        (const float*)d_in[6],  (const float*)d_in[7],  (const float*)d_in[8],
        (const float*)d_in[9],  (const float*)d_in[10], (const float*)d_in[11],
        (const float*)d_in[12], (const float*)d_in[13], (const float*)d_in[14],
        (const float*)d_in[15], (const float*)d_in[16], (const float*)d_in[17],
        (const float*)d_in[18], (float*)d_out);
}

// Round 15
// 173.932 us; speedup vs baseline: 1.2020x; 1.1909x over previous
//
#include <hip/hip_runtime.h>
#include <math.h>

#define LOOKBACK 336
#define NFEAT    164
#define HORIZON  96
#define DMODEL   64
#define DSTATE   16
#define DINNER   128
#define MLPH     64
#define BATCH    512
#define XCP      132
#define NG       4      // channel-groups (time segments) per block
#define GSEG     84     // timesteps per group
#define CHK      12     // timesteps per chunk
#define NCH      7      // chunks per group (7*12 = 84)

typedef float v2f __attribute__((ext_vector_type(2)));

__device__ __forceinline__ float fast_rcp(float x) { return __builtin_amdgcn_rcpf(x); }
__device__ __forceinline__ float silu_f(float x) {
    return x * fast_rcp(1.f + __expf(-x));
}

// R12 structure (60 VGPR / 2 blocks/CU — VGPR<=64 is the occupancy cliff for
// 512-thread blocks, measured R11-R14). Only change vs R12: A2 uses the R8
// 2t x 2j tile on 60 tasks in wave 0 of each group (wave 1 exec-masked off),
// cutting per-group A2 LDS-pipe instructions from 192 to 128 b128 per chunk.
__global__ __launch_bounds__(512, 2) void mamba_one(
    const float* __restrict__ x_raw,   const float* __restrict__ x_features,
    const float* __restrict__ embed_W, const float* __restrict__ embed_b,
    const float* __restrict__ in_W,
    const float* __restrict__ conv_W,  const float* __restrict__ conv_b,
    const float* __restrict__ xproj_W, const float* __restrict__ dt_W,
    const float* __restrict__ dt_b,    const float* __restrict__ A_log,
    const float* __restrict__ Dvec,    const float* __restrict__ out_W,
    const float* __restrict__ mlp_W1,  const float* __restrict__ mlp_b1,
    const float* __restrict__ mlp_W2,  const float* __restrict__ mlp_b2,
    const float* __restrict__ head_W,  const float* __restrict__ head_b,
    float* __restrict__ out)
{
    __shared__ __align__(16) float xrl[344];              // xrl[i]=x_raw[i-3]
    __shared__ __align__(16) float xprojT[20*XCP];
    __shared__ __align__(16) float xcbuf[2][NG][CHK*XCP]; // double-buffered conv out
    __shared__ __align__(16) float Bsh[NG][CHK][DSTATE];
    __shared__ __align__(16) float dtraw[NG][CHK][4];
    __shared__ float xcl[DINNER], zsil[DINNER], Cl[DSTATE], yv[DINNER];
    __shared__ float hfin[96], mlph[MLPH];

    const int tid = threadIdx.x;
    const int b   = blockIdx.x;
    const int g   = tid >> 7;            // group 0..3 (2 waves, wave-uniform)
    const int ch  = tid & 127;

    // ---- staging ----
    for (int i = tid; i < 339; i += 512)
        xrl[i] = (i >= 3) ? x_raw[b*LOOKBACK + i - 3] : 0.f;
    for (int idx = tid; idx < 20*DINNER; idx += 512) {
        int jj = idx >> 7, d = idx & 127;
        xprojT[jj*XCP + d] = xproj_W[d*36 + jj];
    }

    // ---- per-thread channel params ----
    float w1 = 0.f, w0 = 0.f;
    for (int dm = 0; dm < DMODEL; ++dm) {
        float w = in_W[dm*(2*DINNER) + ch];
        w1 = fmaf(embed_W[dm], w, w1);
        w0 = fmaf(embed_b[dm], w, w0);
    }
    const float4 cw = *(const float4*)&conv_W[ch*4];
    const float  cb = conv_b[ch];
    const float dtw0 = dt_W[ch],       dtw1 = dt_W[128 + ch],
                dtw2 = dt_W[256 + ch], dtw3 = dt_W[384 + ch];
    const float dtb_r = dt_b[ch];
    bool structured = true;
    #pragma unroll
    for (int i = 0; i < 16; ++i) {
        float a = __expf(A_log[ch*DSTATE + i]);
        float ex = (float)(i + 1);
        structured = structured && (fabsf(a - ex) < 1e-3f * ex);
    }
    const bool sfast = __all(structured);
    __syncthreads();   // xrl/xprojT ready

    // ---- conv chunk 0 into buffer 0 ----
    {
        float* xw = &xcbuf[0][g][0];
        const float* xr = &xrl[g*GSEG];
        if (g == 0) {        // zero-padded taps at sequence start
            for (int tt = 0; tt < CHK; ++tt) {
                float acc = cb;
                if (tt >= 3) acc = fmaf(fmaf(xr[tt],   w1, w0), cw.x, acc);
                if (tt >= 2) acc = fmaf(fmaf(xr[tt+1], w1, w0), cw.y, acc);
                if (tt >= 1) acc = fmaf(fmaf(xr[tt+2], w1, w0), cw.z, acc);
                acc = fmaf(fmaf(xr[tt+3], w1, w0), cw.w, acc);
                xw[tt*XCP + ch] = silu_f(acc);
            }
        } else {
            float e0 = fmaf(xr[0], w1, w0);
            float e1 = fmaf(xr[1], w1, w0);
            float e2 = fmaf(xr[2], w1, w0);
            #pragma unroll
            for (int tt = 0; tt < CHK; ++tt) {
                float e3 = fmaf(xr[tt+3], w1, w0);
                float acc = cb + e0*cw.x + e1*cw.y + e2*cw.z + e3*cw.w;
                xw[tt*XCP + ch] = silu_f(acc);
                e0 = e1; e1 = e2; e2 = e3;
            }
        }
    }
    __syncthreads();

    // ---- main loop: A2(c) | bar | scan(c) + conv(c+1) | bar ----
    v2f h01={0,0},h23={0,0},h45={0,0},h67={0,0},
        h89={0,0},hAB={0,0},hCD={0,0},hEF={0,0};
    float dacc = 0.f;

    for (int c = 0; c < NCH; ++c) {
        const int buf = c & 1;

        // A2: [12x128]@[128x20] per group; 60 tasks = 6 t-pairs x 10 j-pairs,
        // all in wave 0 of the group (ch<60); wave 1 skips (execz) -> per-group
        // LDS issue = 128 b128 per chunk (was 192 with 1t x 2j on 120 tasks).
        if (ch < 60) {
            const int tg = ch / 10;
            const int j0 = (ch - tg*10) * 2;
            const int t0 = tg*2;
            const float* p0 = &xprojT[j0*XCP];
            const float* p1 = &xprojT[(j0+1)*XCP];
            const float* x0 = &xcbuf[buf][g][t0*XCP];
            const float* x1 = &xcbuf[buf][g][(t0+1)*XCP];
            v2f a00 = {0,0}, a01 = {0,0}, a10 = {0,0}, a11 = {0,0};
            #pragma unroll 8
            for (int d = 0; d < DINNER; d += 4) {
                float4 xv0 = *(const float4*)(x0 + d);
                float4 xv1 = *(const float4*)(x1 + d);
                float4 q0  = *(const float4*)(p0 + d);
                float4 q1  = *(const float4*)(p1 + d);
                v2f x0l = {xv0.x, xv0.y}, x0h = {xv0.z, xv0.w};
                v2f x1l = {xv1.x, xv1.y}, x1h = {xv1.z, xv1.w};
                v2f q0l = {q0.x, q0.y},   q0h = {q0.z, q0.w};
                v2f q1l = {q1.x, q1.y},   q1h = {q1.z, q1.w};
                a00 = __builtin_elementwise_fma(x0l, q0l, a00);
                a00 = __builtin_elementwise_fma(x0h, q0h, a00);
                a01 = __builtin_elementwise_fma(x0l, q1l, a01);
                a01 = __builtin_elementwise_fma(x0h, q1h, a01);
                a10 = __builtin_elementwise_fma(x1l, q0l, a10);
                a10 = __builtin_elementwise_fma(x1h, q0h, a10);
                a11 = __builtin_elementwise_fma(x1l, q1l, a11);
                a11 = __builtin_elementwise_fma(x1h, q1h, a11);
            }
            float r00 = a00.x + a00.y, r01 = a01.x + a01.y;
            float r10 = a10.x + a10.y, r11 = a11.x + a11.y;
            if (j0 < 4) {
                *(float2*)&dtraw[g][t0][j0]   = make_float2(r00, r01);
                *(float2*)&dtraw[g][t0+1][j0] = make_float2(r10, r11);
            } else {
                *(float2*)&Bsh[g][t0][j0-4]   = make_float2(r00, r01);
                *(float2*)&Bsh[g][t0+1][j0-4] = make_float2(r10, r11);
            }
        }
        __syncthreads();

        // scan chunk c (u from LDS; dt/B broadcast reads)
        const float* xs = &xcbuf[buf][g][0];
        if (__builtin_expect(sfast, 1)) {
            #pragma unroll
            for (int tt = 0; tt < CHK; ++tt) {
                float4 dr = *(const float4*)&dtraw[g][tt][0];    // broadcast
                float dv = fmaf(dr.x, dtw0, fmaf(dr.y, dtw1,
                           fmaf(dr.z, dtw2, fmaf(dr.w, dtw3, dtb_r))));
                float e  = __expf(dv);
                float p  = 1.f + e;
                float r  = fast_rcp(p);                  // exp(-delta)
                float dl = (dv > 80.f) ? dv : __logf(p); // delta
                dacc += dl;
                float ux = dl * xs[tt*XCP + ch];
                float4 B0 = *(const float4*)&Bsh[g][tt][0];
                float4 B1 = *(const float4*)&Bsh[g][tt][4];
                float4 B2 = *(const float4*)&Bsh[g][tt][8];
                float4 B3 = *(const float4*)&Bsh[g][tt][12];
                float r2 = r*r;
                v2f r2v = {r2, r2};
                v2f p01 = {r, r2};
                v2f p23 = p01*r2v, p45 = p23*r2v, p67 = p45*r2v, p89 = p67*r2v,
                    pAB = p89*r2v, pCD = pAB*r2v, pEF = pCD*r2v;
                v2f uxv = {ux, ux};
                h01 = __builtin_elementwise_fma(p01, h01, uxv*(v2f){B0.x,B0.y});
                h23 = __builtin_elementwise_fma(p23, h23, uxv*(v2f){B0.z,B0.w});
                h45 = __builtin_elementwise_fma(p45, h45, uxv*(v2f){B1.x,B1.y});
                h67 = __builtin_elementwise_fma(p67, h67, uxv*(v2f){B1.z,B1.w});
                h89 = __builtin_elementwise_fma(p89, h89, uxv*(v2f){B2.x,B2.y});
                hAB = __builtin_elementwise_fma(pAB, hAB, uxv*(v2f){B2.z,B2.w});
                hCD = __builtin_elementwise_fma(pCD, hCD, uxv*(v2f){B3.x,B3.y});
                hEF = __builtin_elementwise_fma(pEF, hEF, uxv*(v2f){B3.z,B3.w});
            }
        } else {
            const float* Arow = A_log + ch*DSTATE;
            for (int tt = 0; tt < CHK; ++tt) {
                float4 dr = *(const float4*)&dtraw[g][tt][0];
                float dv = fmaf(dr.x, dtw0, fmaf(dr.y, dtw1,
                           fmaf(dr.z, dtw2, fmaf(dr.w, dtw3, dtb_r))));
                float e  = __expf(dv);
                float dl = (dv > 15.f) ? dv : __logf(1.f + e);
                dacc += dl;
                float ux = dl * xs[tt*XCP + ch];
                const float* Br = &Bsh[g][tt][0];
                float hv[16] = {h01.x,h01.y,h23.x,h23.y,h45.x,h45.y,h67.x,h67.y,
                                h89.x,h89.y,hAB.x,hAB.y,hCD.x,hCD.y,hEF.x,hEF.y};
                for (int i = 0; i < 16; ++i)
                    hv[i] = fmaf(__expf(-__expf(Arow[i])*dl), hv[i], ux*Br[i]);
                h01=(v2f){hv[0],hv[1]};   h23=(v2f){hv[2],hv[3]};
                h45=(v2f){hv[4],hv[5]};   h67=(v2f){hv[6],hv[7]};
                h89=(v2f){hv[8],hv[9]};   hAB=(v2f){hv[10],hv[11]};
                hCD=(v2f){hv[12],hv[13]}; hEF=(v2f){hv[14],hv[15]};
            }
        }

        // conv chunk c+1 into the other buffer (same phase as scan: its
        // independent fma/silu stream fills the scan's trans latency)
        if (c + 1 < NCH) {
            float* xw = &xcbuf[buf^1][g][0];
            const float* xr = &xrl[g*GSEG + (c+1)*CHK];
            float e0 = fmaf(xr[0], w1, w0);
            float e1 = fmaf(xr[1], w1, w0);
            float e2 = fmaf(xr[2], w1, w0);
            float v = 0.f;
            #pragma unroll
            for (int tt = 0; tt < CHK; ++tt) {
                float e3 = fmaf(xr[tt+3], w1, w0);
                float acc = cb + e0*cw.x + e1*cw.y + e2*cw.z + e3*cw.w;
                v = silu_f(acc);
                xw[tt*XCP + ch] = v;
                e0 = e1; e1 = e2; e2 = e3;
            }
            if (g == NG-1 && c + 1 == NCH-1) xcl[ch] = v;    // t = 335
        }
        __syncthreads();
    }

    // ---- write partials to LDS overlay (SoA: stride-1 b32, conflict-free) ----
    float* hpart = &xcbuf[0][0][0];      // needs 16*512+512 = 8704 <= 12672
    float* dsum  = hpart + 16*512;
    {
        const int gid = g*128 + ch;
        float hv[16] = {h01.x,h01.y,h23.x,h23.y,h45.x,h45.y,h67.x,h67.y,
                        h89.x,h89.y,hAB.x,hAB.y,hCD.x,hCD.y,hEF.x,hEF.y};
        #pragma unroll
        for (int i = 0; i < 16; ++i) hpart[i*512 + gid] = hv[i];
        dsum[gid] = dacc;
    }
    __syncthreads();

    // ---- E1 (parallel): combine | z-gate | C | mlp1 ----
    float H[16];
    if (tid < 128) {
        #pragma unroll
        for (int i = 0; i < 16; ++i) H[i] = hpart[i*512 + tid];
        for (int gg = 1; gg < NG; ++gg) {
            float D = dsum[gg*128 + tid];
            if (structured) {
                float r = __expf(-D);
                float pw = 1.f;
                #pragma unroll
                for (int i = 0; i < 16; ++i) {
                    pw *= r;                      // r^(i+1)
                    H[i] = fmaf(pw, H[i], hpart[i*512 + gg*128 + tid]);
                }
            } else {
                #pragma unroll
                for (int i = 0; i < 16; ++i)
                    H[i] = fmaf(__expf(-__expf(A_log[tid*DSTATE+i])*D),
                                H[i], hpart[i*512 + gg*128 + tid]);
            }
        }
    } else if (tid < 256) {
        const int c2 = tid - 128;                 // z-gate channel
        float a1 = 0.f, a0 = 0.f;
        for (int dm = 0; dm < DMODEL; ++dm) {
            float w = in_W[dm*(2*DINNER) + DINNER + c2];
            a1 = fmaf(embed_W[dm], w, a1);
            a0 = fmaf(embed_b[dm], w, a0);
        }
        float zv = fmaf(xrl[338], a1, a0);        // x_raw[335]
        zsil[c2] = silu_f(zv);
    } else if (tid < 320) {
        const int lane = tid - 256;               // C at t=335 (one wave)
        const int n = lane & 15, q = lane >> 4;
        float acc = 0.f;
        for (int d = q*32; d < q*32 + 32; ++d)
            acc = fmaf(xcl[d], xproj_W[d*36 + 20 + n], acc);
        acc += __shfl_xor(acc, 16);
        acc += __shfl_xor(acc, 32);
        if (lane < 16) Cl[n] = acc;
    } else if (tid >= 384) {
        const int lane = tid - 384;               // mlp1 (2 waves)
        const int j = lane >> 1, k = lane & 1;
        const float* xf = x_features + b*NFEAT;
        float acc = 0.f;
        const int f0 = k*82, f1 = (k ? NFEAT : 82);
        for (int f = f0; f < f1; ++f)
            acc = fmaf(xf[f], mlp_W1[f*MLPH + j], acc);
        acc += __shfl_xor(acc, 1);
        if (k == 0) mlph[j] = fmaxf(acc + mlp_b1[j], 0.f);
    }
    __syncthreads();

    // ---- E2: y (tid<128) | mlp2 (tid 128..191) ----
    if (tid < 128) {
        float acc = 0.f;
        #pragma unroll
        for (int i = 0; i < 16; ++i) acc = fmaf(H[i], Cl[i], acc);
        float y = acc + xcl[tid]*Dvec[tid];
        yv[tid] = y * zsil[tid];
    } else if (tid < 192) {
        const int lane = tid - 128;
        const int j = lane >> 1, k = lane & 1;
        float acc = 0.f;
        for (int kk = k*32; kk < k*32 + 32; ++kk)
            acc = fmaf(mlph[kk], mlp_W2[kk*32 + j], acc);
        acc += __shfl_xor(acc, 1);
        if (k == 0) hfin[64 + j] = acc + mlp_b2[j];
    }
    __syncthreads();

    // ---- E3: out projection (tid<256) ----
    if (tid < 256) {
        const int o = tid >> 2, k = tid & 3;
        float acc = 0.f;
        for (int d = k*32; d < k*32 + 32; ++d)
            acc = fmaf(yv[d], out_W[d*DMODEL + o], acc);
        acc += __shfl_xor(acc, 1);
        acc += __shfl_xor(acc, 2);
        if (k == 0) hfin[o] = acc;
    }
    __syncthreads();

    // ---- E4: head ----
    if (tid < 192) {
        const int o = tid >> 1, k = tid & 1;
        float acc = 0.f;
        for (int i = k*48; i < k*48 + 48; ++i)
            acc = fmaf(hfin[i], head_W[i*HORIZON + o], acc);
        acc += __shfl_xor(acc, 1);
        if (k == 0) out[b*HORIZON + o] = acc + head_b[o];
    }
}

extern "C" void kernel_launch(void* const* d_in, const int* in_sizes, int n_in,
                              void* d_out, int out_size, void* d_ws, size_t ws_size,
                              hipStream_t stream) {
    (void)in_sizes; (void)n_in; (void)out_size; (void)d_ws; (void)ws_size;
    mamba_one<<<BATCH, 512, 0, stream>>>(
        (const float*)d_in[0],  (const float*)d_in[1],  (const float*)d_in[2],
        (const float*)d_in[3],  (const float*)d_in[4],  (const float*)d_in[5],
        (const float*)d_in[6],  (const float*)d_in[7],  (const float*)d_in[8],
        (const float*)d_in[9],  (const float*)d_in[10], (const float*)d_in[11],
        (const float*)d_in[12], (const float*)d_in[13], (const float*)d_in[14],
        (const float*)d_in[15], (const float*)d_in[16], (const float*)d_in[17],
        (const float*)d_in[18], (float*)d_out);
}